// Round 1
// baseline (191.409 us; speedup 1.0000x reference)
//
#include <hip/hip_runtime.h>
#include <float.h>
#include <math.h>

#define BB 32
#define SS 1024
#define DD 512

// K1: copy x -> out, local_scores[row] = dot(x[row,:], w_score) + b_score
__global__ __launch_bounds__(256) void k_copy_localscore(
    const float* __restrict__ x, const float* __restrict__ w_score,
    const float* __restrict__ b_score, float* __restrict__ out_x,
    float* __restrict__ local_scores)
{
    int row  = blockIdx.x * 4 + (threadIdx.x >> 6);
    int lane = threadIdx.x & 63;
    const float4* xr = (const float4*)(x + (size_t)row * DD);
    float4*       orow = (float4*)(out_x + (size_t)row * DD);
    const float4* wr = (const float4*)w_score;
    float4 a0 = xr[lane];
    float4 a1 = xr[lane + 64];
    orow[lane]      = a0;
    orow[lane + 64] = a1;
    float4 w0 = wr[lane];
    float4 w1 = wr[lane + 64];
    float sum = a0.x*w0.x + a0.y*w0.y + a0.z*w0.z + a0.w*w0.w
              + a1.x*w1.x + a1.y*w1.y + a1.z*w1.z + a1.w*w1.w;
    #pragma unroll
    for (int m = 32; m >= 1; m >>= 1) sum += __shfl_xor(sum, m, 64);
    if (lane == 0) local_scores[row] = sum + b_score[0];
}

// K2: xsum[b,d] = sum_s x[b,s,d]
__global__ __launch_bounds__(128) void k_xsum(
    const float* __restrict__ x, float* __restrict__ xsum)
{
    int b = blockIdx.y;
    int d = blockIdx.x * 128 + threadIdx.x;
    const float* xb = x + (size_t)b * SS * DD + d;
    float acc = 0.f;
    #pragma unroll 8
    for (int s = 0; s < SS; ++s) acc += xb[(size_t)s * DD];
    xsum[b * DD + d] = acc;
}

// K3: per-batch: ksum = Wk^T xsum + S*bk ; t = bq . ksum ; v = Wq ksum
__global__ __launch_bounds__(256) void k_project(
    const float* __restrict__ xsum, const float* __restrict__ Wq,
    const float* __restrict__ bq, const float* __restrict__ Wk,
    const float* __restrict__ bk, float* __restrict__ v, float* __restrict__ t)
{
    __shared__ float xs[DD];
    __shared__ float ks[DD];
    __shared__ float red[256];
    int b = blockIdx.x, tid = threadIdx.x;
    xs[tid]       = xsum[b * DD + tid];
    xs[tid + 256] = xsum[b * DD + tid + 256];
    __syncthreads();
    #pragma unroll
    for (int i = 0; i < 2; ++i) {
        int e = tid + i * 256;
        float acc = 0.f;
        for (int d = 0; d < DD; ++d) acc += xs[d] * Wk[d * DD + e];
        ks[e] = acc + (float)SS * bk[e];
    }
    __syncthreads();
    // t[b] = bq . ksum
    float tp = bq[tid] * ks[tid] + bq[tid + 256] * ks[tid + 256];
    red[tid] = tp; __syncthreads();
    for (int off = 128; off >= 1; off >>= 1) {
        if (tid < off) red[tid] += red[tid + off];
        __syncthreads();
    }
    if (tid == 0) t[b] = red[0];
    // v[b,d] = sum_e Wq[d,e] * ks[e]
    #pragma unroll
    for (int i = 0; i < 2; ++i) {
        int d = tid + i * 256;
        float acc = 0.f;
        for (int e = 0; e < DD; ++e) acc += Wq[d * DD + e] * ks[e];
        v[b * DD + d] = acc;
    }
}

// K4: g_scores[row] = (dot(x[row,:], v[b]) + t[b]) / sqrt(D)
__global__ __launch_bounds__(256) void k_gscore(
    const float* __restrict__ x, const float* __restrict__ v,
    const float* __restrict__ t, float* __restrict__ g_scores)
{
    int row  = blockIdx.x * 4 + (threadIdx.x >> 6);
    int lane = threadIdx.x & 63;
    int b = row >> 10;  // S = 1024
    const float4* xr = (const float4*)(x + (size_t)row * DD);
    const float4* vr = (const float4*)(v + b * DD);
    float4 a0 = xr[lane], a1 = xr[lane + 64];
    float4 v0 = vr[lane], v1 = vr[lane + 64];
    float sum = a0.x*v0.x + a0.y*v0.y + a0.z*v0.z + a0.w*v0.w
              + a1.x*v1.x + a1.y*v1.y + a1.z*v1.z + a1.w*v1.w;
    #pragma unroll
    for (int m = 32; m >= 1; m >>= 1) sum += __shfl_xor(sum, m, 64);
    if (lane == 0) g_scores[row] = (sum + t[b]) * 0.04419417382415922f;
}

// K5: masked softmax of both score sets, beta-combine into one weight per (b,s)
__global__ __launch_bounds__(256) void k_softmax_combine(
    const float* __restrict__ local_scores, const float* __restrict__ g_scores,
    const int* __restrict__ x_len, const int* __restrict__ slot_idx,
    const float* __restrict__ beta_raw, float* __restrict__ w_comb)
{
    __shared__ float red[256];
    int b = blockIdx.x, tid = threadIdx.x;
    int len = x_len[b];
    float ls[4], gs[4];
    float lmax = -FLT_MAX, gmax = -FLT_MAX;
    #pragma unroll
    for (int i = 0; i < 4; ++i) {
        int s = tid + i * 256;
        bool valid = s < len;
        ls[i] = valid ? local_scores[b * SS + s] : -FLT_MAX;
        gs[i] = valid ? g_scores[b * SS + s] : -FLT_MAX;
        lmax = fmaxf(lmax, ls[i]);
        gmax = fmaxf(gmax, gs[i]);
    }
    red[tid] = lmax; __syncthreads();
    for (int off = 128; off >= 1; off >>= 1) {
        if (tid < off) red[tid] = fmaxf(red[tid], red[tid + off]);
        __syncthreads();
    }
    lmax = red[0]; __syncthreads();
    red[tid] = gmax; __syncthreads();
    for (int off = 128; off >= 1; off >>= 1) {
        if (tid < off) red[tid] = fmaxf(red[tid], red[tid + off]);
        __syncthreads();
    }
    gmax = red[0]; __syncthreads();

    float le[4], ge[4];
    float lsum = 0.f, gsum = 0.f;
    #pragma unroll
    for (int i = 0; i < 4; ++i) {
        int s = tid + i * 256;
        bool valid = s < len;
        le[i] = valid ? expf(ls[i] - lmax) : 0.f;
        ge[i] = valid ? expf(gs[i] - gmax) : 0.f;
        lsum += le[i];
        gsum += ge[i];
    }
    red[tid] = lsum; __syncthreads();
    for (int off = 128; off >= 1; off >>= 1) {
        if (tid < off) red[tid] += red[tid + off];
        __syncthreads();
    }
    lsum = red[0]; __syncthreads();
    red[tid] = gsum; __syncthreads();
    for (int off = 128; off >= 1; off >>= 1) {
        if (tid < off) red[tid] += red[tid + off];
        __syncthreads();
    }
    gsum = red[0]; __syncthreads();

    float br = beta_raw[slot_idx[0]];
    float beta = 1.f / (1.f + expf(-br));
    float rl = beta / lsum;
    float rg = (1.f - beta) / gsum;
    #pragma unroll
    for (int i = 0; i < 4; ++i) {
        int s = tid + i * 256;
        w_comb[b * SS + s] = le[i] * rl + ge[i] * rg;
    }
}

// K6: c[b,d] = sum_s w_comb[b,s] * x[b,s,d]
__global__ __launch_bounds__(128) void k_context(
    const float* __restrict__ x, const float* __restrict__ w_comb,
    float* __restrict__ out_c)
{
    int b = blockIdx.y;
    int d = blockIdx.x * 128 + threadIdx.x;
    const float* xb = x + (size_t)b * SS * DD + d;
    const float* wb = w_comb + b * SS;
    float acc = 0.f;
    #pragma unroll 8
    for (int s = 0; s < SS; ++s) acc += wb[s] * xb[(size_t)s * DD];
    out_c[b * DD + d] = acc;
}

extern "C" void kernel_launch(void* const* d_in, const int* in_sizes, int n_in,
                              void* d_out, int out_size, void* d_ws, size_t ws_size,
                              hipStream_t stream) {
    const float* x        = (const float*)d_in[0];
    const int*   x_len    = (const int*)d_in[1];
    const int*   slot_idx = (const int*)d_in[2];
    const float* w_score  = (const float*)d_in[3];
    const float* b_score  = (const float*)d_in[4];
    const float* Wq       = (const float*)d_in[5];
    const float* bq       = (const float*)d_in[6];
    const float* Wk       = (const float*)d_in[7];
    const float* bk       = (const float*)d_in[8];
    const float* beta_raw = (const float*)d_in[9];

    float* out   = (float*)d_out;
    float* out_x = out;                           // [B,S,D]
    float* out_c = out + (size_t)BB * SS * DD;    // [B,D]

    float* ws = (float*)d_ws;
    float* local_scores = ws;                     // B*S
    float* g_scores     = ws + BB * SS;           // B*S
    float* w_comb       = ws + 2 * BB * SS;       // B*S
    float* xsum         = ws + 3 * BB * SS;       // B*D
    float* v            = ws + 3 * BB * SS + BB * DD; // B*D
    float* t            = ws + 3 * BB * SS + 2 * BB * DD; // B

    k_copy_localscore<<<BB * SS / 4, 256, 0, stream>>>(x, w_score, b_score, out_x, local_scores);
    k_xsum<<<dim3(DD / 128, BB), 128, 0, stream>>>(x, xsum);
    k_project<<<BB, 256, 0, stream>>>(xsum, Wq, bq, Wk, bk, v, t);
    k_gscore<<<BB * SS / 4, 256, 0, stream>>>(x, v, t, g_scores);
    k_softmax_combine<<<BB, 256, 0, stream>>>(local_scores, g_scores, x_len, slot_idx, beta_raw, w_comb);
    k_context<<<dim3(DD / 128, BB), 128, 0, stream>>>(x, w_comb, out_c);
}

// Round 2
// 81.295 us; speedup vs baseline: 2.3545x; 2.3545x over previous
//
#include <hip/hip_runtime.h>
#include <float.h>
#include <math.h>

#define BB 32
#define SS 1024
#define DD 512

// ---------------- K1: fused copy + local_score + xsum partials ----------------
// grid (BB, 8 schunks), 256 threads (4 waves). Each wave handles 32 rows.
__global__ __launch_bounds__(256) void k_main1(
    const float* __restrict__ x, const float* __restrict__ w_score,
    const float* __restrict__ b_score, float* __restrict__ out_x,
    float* __restrict__ local_scores, float* __restrict__ xsum_part)
{
    __shared__ float lds[4 * DD];
    int b = blockIdx.x, sc = blockIdx.y;
    int wave = threadIdx.x >> 6, lane = threadIdx.x & 63;
    int row0 = b * SS + sc * 128 + wave * 32;

    const float4* wr = (const float4*)w_score;
    float4 w0 = wr[lane];
    float4 w1 = wr[lane + 64];
    float bs = b_score[0];

    float4 acc0 = {0.f, 0.f, 0.f, 0.f}, acc1 = {0.f, 0.f, 0.f, 0.f};

    for (int r = 0; r < 32; ++r) {
        int row = row0 + r;
        const float4* xr = (const float4*)(x + (size_t)row * DD);
        float4*       orow = (float4*)(out_x + (size_t)row * DD);
        float4 a0 = xr[lane];
        float4 a1 = xr[lane + 64];
        orow[lane]      = a0;
        orow[lane + 64] = a1;
        float p = a0.x*w0.x + a0.y*w0.y + a0.z*w0.z + a0.w*w0.w
                + a1.x*w1.x + a1.y*w1.y + a1.z*w1.z + a1.w*w1.w;
        #pragma unroll
        for (int m = 32; m >= 1; m >>= 1) p += __shfl_xor(p, m, 64);
        if (lane == 0) local_scores[row] = p + bs;
        acc0.x += a0.x; acc0.y += a0.y; acc0.z += a0.z; acc0.w += a0.w;
        acc1.x += a1.x; acc1.y += a1.y; acc1.z += a1.z; acc1.w += a1.w;
    }
    // cross-wave column reduce
    float4* l4 = (float4*)lds;
    l4[wave * 128 + lane]      = acc0;
    l4[wave * 128 + lane + 64] = acc1;
    __syncthreads();
    int tid = threadIdx.x;
    #pragma unroll
    for (int i = 0; i < 2; ++i) {
        int d = tid + i * 256;
        float s = lds[d] + lds[DD + d] + lds[2 * DD + d] + lds[3 * DD + d];
        xsum_part[((size_t)b * 8 + sc) * DD + d] = s;
    }
}

// ---------------- K2: ks partials: ks_part[dc][b][e] ----------------
// grid (8 dchunk, 2 eblock, 4 bgroup), 256 threads.
__global__ __launch_bounds__(256) void k_ks(
    const float* __restrict__ xsum_part, const float* __restrict__ Wk,
    float* __restrict__ ks_part)
{
    __shared__ float xs[8][64];
    int dc = blockIdx.x, eb = blockIdx.y, bg = blockIdx.z;
    int tid = threadIdx.x;
    int e = eb * 256 + tid;
    // load xs[bi][dl] = sum_sc xsum_part[b][sc][d]
    #pragma unroll
    for (int k = 0; k < 2; ++k) {
        int i = tid + k * 256;
        int bi = i >> 6, dl = i & 63;
        int b = bg * 8 + bi, d = dc * 64 + dl;
        float v = 0.f;
        #pragma unroll
        for (int scc = 0; scc < 8; ++scc)
            v += xsum_part[((size_t)b * 8 + scc) * DD + d];
        xs[bi][dl] = v;
    }
    __syncthreads();
    float acc[8] = {0,0,0,0,0,0,0,0};
    #pragma unroll 8
    for (int dl = 0; dl < 64; ++dl) {
        float w = Wk[(size_t)(dc * 64 + dl) * DD + e];
        #pragma unroll
        for (int bi = 0; bi < 8; ++bi) acc[bi] += xs[bi][dl] * w;
    }
    #pragma unroll
    for (int bi = 0; bi < 8; ++bi) {
        int b = bg * 8 + bi;
        ks_part[((size_t)dc * BB + b) * DD + e] = acc[bi];
    }
}

// ---------------- K3: v partials + t partials ----------------
// grid (8 echunk, 2 dblock, 4 bgroup), 256 threads.
// v_part[ec][b][d] = sum_{e in chunk} ks[b][e] * Wq[d][e]
// ks[b][e] = sum_dc ks_part[dc][b][e] + SS*bk[e]
__global__ __launch_bounds__(256) void k_v(
    const float* __restrict__ ks_part, const float* __restrict__ Wq,
    const float* __restrict__ bq, const float* __restrict__ bk,
    float* __restrict__ v_part, float* __restrict__ t_part)
{
    __shared__ float wq_lds[256 * 65];
    __shared__ float ks_lds[8][64];
    int ec = blockIdx.x, db = blockIdx.y, bg = blockIdx.z;
    int tid = threadIdx.x;
    // load ks for this (bgroup, echunk)
    #pragma unroll
    for (int k = 0; k < 2; ++k) {
        int i = tid + k * 256;
        int bi = i >> 6, el = i & 63;
        int b = bg * 8 + bi, e = ec * 64 + el;
        float val = (float)SS * bk[e];
        #pragma unroll
        for (int dcc = 0; dcc < 8; ++dcc)
            val += ks_part[((size_t)dcc * BB + b) * DD + e];
        ks_lds[bi][el] = val;
    }
    // stage Wq tile [256 d][64 e] into LDS (padded rows)
    #pragma unroll
    for (int it = 0; it < 16; ++it) {
        int idx = tid + it * 256;          // float4 index
        int rowd = idx >> 4, col4 = idx & 15;
        const float4 wv = *(const float4*)(Wq + (size_t)(db * 256 + rowd) * DD + ec * 64 + col4 * 4);
        float* dst = &wq_lds[rowd * 65 + col4 * 4];
        dst[0] = wv.x; dst[1] = wv.y; dst[2] = wv.z; dst[3] = wv.w;
    }
    __syncthreads();
    // t partials (bq . ks) — only db==0 blocks, 8 threads
    if (db == 0 && tid < 8) {
        float ta = 0.f;
        for (int el = 0; el < 64; ++el) ta += bq[ec * 64 + el] * ks_lds[tid][el];
        t_part[ec * BB + bg * 8 + tid] = ta;
    }
    float acc[8] = {0,0,0,0,0,0,0,0};
    #pragma unroll 8
    for (int el = 0; el < 64; ++el) {
        float wq = wq_lds[tid * 65 + el];
        #pragma unroll
        for (int bi = 0; bi < 8; ++bi) acc[bi] += ks_lds[bi][el] * wq;
    }
    int d = db * 256 + tid;
    #pragma unroll
    for (int bi = 0; bi < 8; ++bi) {
        int b = bg * 8 + bi;
        v_part[((size_t)ec * BB + b) * DD + d] = acc[bi];
    }
}

// ---------------- K4: reduce v partials, t partials ----------------
__global__ __launch_bounds__(512) void k_vred(
    const float* __restrict__ v_part, const float* __restrict__ t_part,
    float* __restrict__ v, float* __restrict__ t)
{
    int b = blockIdx.x, tid = threadIdx.x;
    float s = 0.f;
    #pragma unroll
    for (int ec = 0; ec < 8; ++ec) s += v_part[((size_t)ec * BB + b) * DD + tid];
    v[b * DD + tid] = s;
    if (tid == 0) {
        float ts = 0.f;
        #pragma unroll
        for (int ec = 0; ec < 8; ++ec) ts += t_part[ec * BB + b];
        t[b] = ts;
    }
}

// ---------------- K5: g_scores[row] = (x[row,:].v[b] + t[b]) / sqrt(D) ----------------
__global__ __launch_bounds__(256) void k_gscore(
    const float* __restrict__ x, const float* __restrict__ v,
    const float* __restrict__ t, float* __restrict__ g_scores)
{
    int row  = blockIdx.x * 4 + (threadIdx.x >> 6);
    int lane = threadIdx.x & 63;
    int b = row >> 10;
    const float4* xr = (const float4*)(x + (size_t)row * DD);
    const float4* vr = (const float4*)(v + b * DD);
    float4 a0 = xr[lane], a1 = xr[lane + 64];
    float4 v0 = vr[lane], v1 = vr[lane + 64];
    float sum = a0.x*v0.x + a0.y*v0.y + a0.z*v0.z + a0.w*v0.w
              + a1.x*v1.x + a1.y*v1.y + a1.z*v1.z + a1.w*v1.w;
    #pragma unroll
    for (int m = 32; m >= 1; m >>= 1) sum += __shfl_xor(sum, m, 64);
    if (lane == 0) g_scores[row] = (sum + t[b]) * 0.04419417382415922f;
}

// ---------------- K6: masked dual softmax + beta combine ----------------
__global__ __launch_bounds__(256) void k_softmax_combine(
    const float* __restrict__ local_scores, const float* __restrict__ g_scores,
    const int* __restrict__ x_len, const int* __restrict__ slot_idx,
    const float* __restrict__ beta_raw, float* __restrict__ w_comb)
{
    __shared__ float red[256];
    int b = blockIdx.x, tid = threadIdx.x;
    int len = x_len[b];
    float ls[4], gs[4];
    float lmax = -FLT_MAX, gmax = -FLT_MAX;
    #pragma unroll
    for (int i = 0; i < 4; ++i) {
        int s = tid + i * 256;
        bool valid = s < len;
        ls[i] = valid ? local_scores[b * SS + s] : -FLT_MAX;
        gs[i] = valid ? g_scores[b * SS + s] : -FLT_MAX;
        lmax = fmaxf(lmax, ls[i]);
        gmax = fmaxf(gmax, gs[i]);
    }
    red[tid] = lmax; __syncthreads();
    for (int off = 128; off >= 1; off >>= 1) {
        if (tid < off) red[tid] = fmaxf(red[tid], red[tid + off]);
        __syncthreads();
    }
    lmax = red[0]; __syncthreads();
    red[tid] = gmax; __syncthreads();
    for (int off = 128; off >= 1; off >>= 1) {
        if (tid < off) red[tid] = fmaxf(red[tid], red[tid + off]);
        __syncthreads();
    }
    gmax = red[0]; __syncthreads();

    float le[4], ge[4];
    float lsum = 0.f, gsum = 0.f;
    #pragma unroll
    for (int i = 0; i < 4; ++i) {
        int s = tid + i * 256;
        bool valid = s < len;
        le[i] = valid ? expf(ls[i] - lmax) : 0.f;
        ge[i] = valid ? expf(gs[i] - gmax) : 0.f;
        lsum += le[i];
        gsum += ge[i];
    }
    red[tid] = lsum; __syncthreads();
    for (int off = 128; off >= 1; off >>= 1) {
        if (tid < off) red[tid] += red[tid + off];
        __syncthreads();
    }
    lsum = red[0]; __syncthreads();
    red[tid] = gsum; __syncthreads();
    for (int off = 128; off >= 1; off >>= 1) {
        if (tid < off) red[tid] += red[tid + off];
        __syncthreads();
    }
    gsum = red[0]; __syncthreads();

    float br = beta_raw[slot_idx[0]];
    float beta = 1.f / (1.f + expf(-br));
    float rl = beta / lsum;
    float rg = (1.f - beta) / gsum;
    #pragma unroll
    for (int i = 0; i < 4; ++i) {
        int s = tid + i * 256;
        w_comb[b * SS + s] = le[i] * rl + ge[i] * rg;
    }
}

// ---------------- K7: context partials (len-bounded) ----------------
// grid (BB, 4 schunks), 256 threads: c_part[sc][b][d]
__global__ __launch_bounds__(256) void k_context_part(
    const float* __restrict__ x, const float* __restrict__ w_comb,
    const int* __restrict__ x_len, float* __restrict__ c_part)
{
    int b = blockIdx.x, sc = blockIdx.y, tid = threadIdx.x;
    int len = x_len[b];
    int start = sc * 256;
    int end = min(len, start + 256);
    const float* xb = x + (size_t)b * SS * DD;
    const float* wb = w_comb + b * SS;
    float acc0 = 0.f, acc1 = 0.f;
    #pragma unroll 4
    for (int s = start; s < end; ++s) {
        float w = wb[s];
        acc0 += w * xb[(size_t)s * DD + tid];
        acc1 += w * xb[(size_t)s * DD + tid + 256];
    }
    c_part[((size_t)sc * BB + b) * DD + tid]       = acc0;
    c_part[((size_t)sc * BB + b) * DD + tid + 256] = acc1;
}

// ---------------- K8: reduce context partials ----------------
__global__ __launch_bounds__(512) void k_context_red(
    const float* __restrict__ c_part, float* __restrict__ out_c)
{
    int b = blockIdx.x, tid = threadIdx.x;
    float s = 0.f;
    #pragma unroll
    for (int sc = 0; sc < 4; ++sc) s += c_part[((size_t)sc * BB + b) * DD + tid];
    out_c[b * DD + tid] = s;
}

extern "C" void kernel_launch(void* const* d_in, const int* in_sizes, int n_in,
                              void* d_out, int out_size, void* d_ws, size_t ws_size,
                              hipStream_t stream) {
    const float* x        = (const float*)d_in[0];
    const int*   x_len    = (const int*)d_in[1];
    const int*   slot_idx = (const int*)d_in[2];
    const float* w_score  = (const float*)d_in[3];
    const float* b_score  = (const float*)d_in[4];
    const float* Wq       = (const float*)d_in[5];
    const float* bq       = (const float*)d_in[6];
    const float* Wk       = (const float*)d_in[7];
    const float* bk       = (const float*)d_in[8];
    const float* beta_raw = (const float*)d_in[9];

    float* out   = (float*)d_out;
    float* out_x = out;                           // [B,S,D]
    float* out_c = out + (size_t)BB * SS * DD;    // [B,D]

    float* ws = (float*)d_ws;
    float* local_scores = ws;                               // 32768
    float* g_scores     = ws + 32768;                       // 32768
    float* w_comb       = ws + 65536;                       // 32768
    float* xsum_part    = ws + 98304;                       // 32*8*512 = 131072
    float* ks_part      = ws + 229376;                      // 8*32*512 = 131072
    float* v_part       = ws + 360448;                      // 8*32*512 = 131072
    float* t_part       = ws + 491520;                      // 256
    float* v            = ws + 491776;                      // 16384
    float* t            = ws + 508160;                      // 32
    float* c_part       = ws + 508192;                      // 4*32*512 = 65536

    k_main1<<<dim3(BB, 8), 256, 0, stream>>>(x, w_score, b_score, out_x, local_scores, xsum_part);
    k_ks<<<dim3(8, 2, 4), 256, 0, stream>>>(xsum_part, Wk, ks_part);
    k_v<<<dim3(8, 2, 4), 256, 0, stream>>>(ks_part, Wq, bq, bk, v_part, t_part);
    k_vred<<<BB, 512, 0, stream>>>(v_part, t_part, v, t);
    k_gscore<<<BB * SS / 4, 256, 0, stream>>>(x, v, t, g_scores);
    k_softmax_combine<<<BB, 256, 0, stream>>>(local_scores, g_scores, x_len, slot_idx, beta_raw, w_comb);
    k_context_part<<<dim3(BB, 4), 256, 0, stream>>>(x, w_comb, x_len, c_part);
    k_context_red<<<BB, 512, 0, stream>>>(c_part, out_c);
}